// Round 1
// baseline (1872.093 us; speedup 1.0000x reference)
//
#include <hip/hip_runtime.h>
#include <math.h>

#define HW 256
#define CDIM 64
#define NHEAD 8
#define CFULL 512
#define BATCH 4
#define TFRAMES 64
#define NKEY (TFRAMES*HW)            // 16384
#define NSPLIT 8
#define KEYS_PER_SPLIT (NKEY/NSPLIT) // 2048
#define CHUNK 64
#define NCHUNK (KEYS_PER_SPLIT/CHUNK) // 32

#define KLOG10K_64 0.14391156634543589f  // ln(10000)/64

// ---------------- ws layout (floats) ----------------
// wq_mp   : [0]        1536*512 = 786432
// wp_mp   : [786432]   512*512  = 262144
// q       : [1048576]  4*8*256*64 = 524288   (roped, pos 63)   [b][m][p][ch]
// kn      : [1572864]  524288                 (roped, pos 63)   [b][m][p][ch]
// vn      : [2097152]  524288                                   [b][m][p][ch]
// o_part  : [2621440]  32*8*64*256 = 4194304                    [bm][s][ch][p]
// ml      : [6815744]  32*8*2*256 = 131072                      [bm][s][{m,l}][p]
// om      : [6946816]  4*512*256 = 524288                       [b][ic=ch*8+head][p]
// total ~7.47M floats = 29.9 MB

// ---- Kernel 1: mp-normalize both weight matrices (one block per row) ----
__global__ void k_norm(const float* __restrict__ wqkv, const float* __restrict__ wproj,
                       float* __restrict__ wq_mp, float* __restrict__ wp_mp) {
    int row = blockIdx.x;
    const float* src; float* dst;
    if (row < 1536) { src = wqkv + row*CFULL;        dst = wq_mp + row*CFULL; }
    else            { src = wproj + (row-1536)*CFULL; dst = wp_mp + (row-1536)*CFULL; }
    int t = threadIdx.x;                 // 256 threads
    float a = src[t], b = src[t+256];
    float v = a*a + b*b;
    #pragma unroll
    for (int o = 32; o >= 1; o >>= 1) v += __shfl_down(v, o, 64);
    __shared__ float red[4];
    if ((t & 63) == 0) red[t >> 6] = v;
    __syncthreads();
    float ss = red[0] + red[1] + red[2] + red[3];
    float norm = sqrtf(ss);
    const float s512 = 22.627416997969522f;          // sqrt(512)
    float scale = 1.0f / ((1e-4f + norm / s512) * s512);
    dst[t]     = a * scale;
    dst[t+256] = b * scale;
}

// ---- Kernel 2: QKV projection + RoPE(pos=63) on q and new-k ----
// block: (og in [0,96), b); 256 threads = pixel p; each block does 16 output rows
__global__ void k_qkv(const float* __restrict__ x, const float* __restrict__ wq,
                      float* __restrict__ q, float* __restrict__ kn, float* __restrict__ vn) {
    int og = blockIdx.x;
    int b  = blockIdx.y;
    int p  = threadIdx.x;
    const float* xb = x + (long)b*CFULL*HW + p;
    float acc[16];
    #pragma unroll
    for (int i = 0; i < 16; i++) acc[i] = 0.f;
    int obase = og * 16;
    for (int c = 0; c < CFULL; c++) {
        float xv = xb[c*HW];
        #pragma unroll
        for (int i = 0; i < 16; i++) acc[i] += xv * wq[(obase+i)*CFULL + c];
    }
    int sec  = obase >> 9;       // 0=q 1=k 2=v (16 | 512, no straddle)
    int rem  = obase & 511;
    int head = rem >> 6;
    int chb  = rem & 63;         // multiple of 16, rope pairs stay local
    float* dst = (sec == 0) ? q : (sec == 1) ? kn : vn;
    long base = ((long)((b*NHEAD + head)*HW + p)) * CDIM;
    if (sec == 2) {
        #pragma unroll
        for (int i = 0; i < 16; i++) dst[base + chb + i] = acc[i];
    } else {
        const float pos = 63.0f;
        #pragma unroll
        for (int i = 0; i < 16; i += 2) {
            int ch = chb + i;
            float fr = __expf(-(float)ch * KLOG10K_64);
            float sn, cs;
            __sincosf(pos * fr, &sn, &cs);
            float x1 = acc[i], x2 = acc[i+1];
            dst[base + ch]     = x1*cs - x2*sn;
            dst[base + ch + 1] = x1*sn + x2*cs;
        }
    }
}

// ---- Kernel 3: split-K flash attention, f32, one query row per thread ----
__global__ __launch_bounds__(256, 1) void k_attn(
        const float* __restrict__ q, const float* __restrict__ kc, const float* __restrict__ vc,
        const float* __restrict__ kn, const float* __restrict__ vn,
        float* __restrict__ o_part, float* __restrict__ ml) {
    int bm = blockIdx.x;   // b*8+m, 0..31
    int s  = blockIdx.y;   // key split 0..7
    int tq = threadIdx.x;  // query index 0..255
    __shared__ float Ks[CHUNK*CDIM];
    __shared__ float Vs[CHUNK*CDIM];
    float qv[CDIM];
    const float* qp = q + ((long)(bm*HW + tq)) * CDIM;
    #pragma unroll
    for (int i = 0; i < CDIM; i += 4) {
        float4 f = *(const float4*)(qp + i);
        qv[i] = f.x; qv[i+1] = f.y; qv[i+2] = f.z; qv[i+3] = f.w;
    }
    float o[CDIM];
    #pragma unroll
    for (int i = 0; i < CDIM; i++) o[i] = 0.f;
    float mv = -1e30f, l = 0.f;

    int j  = tq >> 2;        // staging: key within chunk
    int cb = (tq & 3) * 16;  // staging: channel base (16 floats per thread)

    for (int chunk = 0; chunk < NCHUNK; chunk++) {
        int g0  = s*KEYS_PER_SPLIT + chunk*CHUNK;   // chunk never straddles a frame
        int tfr = g0 >> 8;                          // frame index = rope position
        int pp  = (g0 & 255) + j;
        const float* ksrc; const float* vsrc;
        if (tfr < 63) {
            long off = ((long)((bm*63 + tfr)*HW + pp)) * CDIM;
            ksrc = kc + off; vsrc = vc + off;
        } else {
            long off = ((long)(bm*HW + pp)) * CDIM;
            ksrc = kn + off; vsrc = vn + off;       // already roped at pos 63
        }
        float tpos = (float)tfr;
        bool rope = (tfr < 63);
        __syncthreads();
        #pragma unroll
        for (int qq = 0; qq < 4; qq++) {
            int ch = cb + qq*4;
            float4 f  = *(const float4*)(ksrc + ch);
            if (rope) {
                float fr0 = __expf(-(float)ch       * KLOG10K_64);
                float fr1 = __expf(-(float)(ch + 2) * KLOG10K_64);
                float s0, c0, s1, c1;
                __sincosf(tpos*fr0, &s0, &c0);
                __sincosf(tpos*fr1, &s1, &c1);
                float4 r;
                r.x = f.x*c0 - f.y*s0;
                r.y = f.x*s0 + f.y*c0;
                r.z = f.z*c1 - f.w*s1;
                r.w = f.z*s1 + f.w*c1;
                f = r;
            }
            *(float4*)&Ks[j*CDIM + ch] = f;
            float4 v4 = *(const float4*)(vsrc + ch);
            *(float4*)&Vs[j*CDIM + ch] = v4;
        }
        __syncthreads();
        for (int k = 0; k < CHUNK; k++) {
            float sc = 0.f;
            const float* kr = &Ks[k*CDIM];
            #pragma unroll
            for (int i = 0; i < CDIM; i += 4) {
                float4 k4 = *(const float4*)(kr + i);
                sc += qv[i]*k4.x + qv[i+1]*k4.y + qv[i+2]*k4.z + qv[i+3]*k4.w;
            }
            sc *= 0.125f;   // 1/sqrt(64)
            if (sc > mv) {  // rare after warm-up: deferred rescale
                float corr = __expf(mv - sc);
                mv = sc;
                l *= corr;
                #pragma unroll
                for (int i = 0; i < CDIM; i++) o[i] *= corr;
            }
            float pj = __expf(sc - mv);
            l += pj;
            const float* vr = &Vs[k*CDIM];
            #pragma unroll
            for (int i = 0; i < CDIM; i += 4) {
                float4 v4 = *(const float4*)(vr + i);
                o[i]   += pj*v4.x; o[i+1] += pj*v4.y;
                o[i+2] += pj*v4.z; o[i+3] += pj*v4.w;
            }
        }
    }
    long ob = ((long)(bm*NSPLIT + s)) * CDIM * HW;
    #pragma unroll
    for (int i = 0; i < CDIM; i++) o_part[ob + (long)i*HW + tq] = o[i];
    long mb = ((long)(bm*NSPLIT + s)) * 2 * HW;
    ml[mb + tq]      = mv;
    ml[mb + HW + tq] = l;
}

// ---- Kernel 4: combine split partials -> om[b][ch*8+head][p] ----
__global__ void k_combine(const float* __restrict__ o_part, const float* __restrict__ ml,
                          float* __restrict__ om) {
    int bm  = blockIdx.x;   // 0..31
    int chg = blockIdx.y;   // 0..3, 16 channels each
    int p   = threadIdx.x;
    float ms[NSPLIT], ls[NSPLIT];
    float mmax = -1e30f;
    #pragma unroll
    for (int s2 = 0; s2 < NSPLIT; s2++) {
        long mb = ((long)(bm*NSPLIT + s2)) * 2 * HW;
        ms[s2] = ml[mb + p];
        ls[s2] = ml[mb + HW + p];
        mmax = fmaxf(mmax, ms[s2]);
    }
    float wgt[NSPLIT];
    float wsum = 0.f;
    #pragma unroll
    for (int s2 = 0; s2 < NSPLIT; s2++) { wgt[s2] = __expf(ms[s2]-mmax); wsum += wgt[s2]*ls[s2]; }
    float inv = 1.0f / wsum;
    int b = bm >> 3, head = bm & 7;
    for (int ch = chg*16; ch < chg*16 + 16; ch++) {
        float acc = 0.f;
        #pragma unroll
        for (int s2 = 0; s2 < NSPLIT; s2++)
            acc += wgt[s2] * o_part[(((long)(bm*NSPLIT + s2))*CDIM + ch)*HW + p];
        om[((long)(b*CFULL + ch*NHEAD + head))*HW + p] = acc * inv;
    }
}

// ---- Kernel 5: output projection + mp_sum residual ----
__global__ void k_proj(const float* __restrict__ om, const float* __restrict__ wp,
                       const float* __restrict__ x, float* __restrict__ out) {
    int og = blockIdx.x;  // 0..31, 16 rows each
    int b  = blockIdx.y;
    int p  = threadIdx.x;
    float acc[16];
    #pragma unroll
    for (int i = 0; i < 16; i++) acc[i] = 0.f;
    const float* ob = om + (long)b*CFULL*HW + p;
    for (int c = 0; c < CFULL; c++) {
        float ov = ob[c*HW];
        #pragma unroll
        for (int i = 0; i < 16; i++) acc[i] += ov * wp[(og*16+i)*CFULL + c];
    }
    const float inv_mp = 1.3130643285972254f;  // 1/sqrt(0.7^2+0.3^2)
    #pragma unroll
    for (int i = 0; i < 16; i++) {
        int oc = og*16 + i;
        long idx = ((long)(b*CFULL + oc))*HW + p;
        out[idx] = (x[idx]*0.7f + acc[i]*0.3f) * inv_mp;
    }
}

extern "C" void kernel_launch(void* const* d_in, const int* in_sizes, int n_in,
                              void* d_out, int out_size, void* d_ws, size_t ws_size,
                              hipStream_t stream) {
    const float* x     = (const float*)d_in[0];
    const float* kc    = (const float*)d_in[1];
    const float* vc    = (const float*)d_in[2];
    const float* wqkv  = (const float*)d_in[3];
    const float* wproj = (const float*)d_in[4];
    float* out = (float*)d_out;
    float* ws  = (float*)d_ws;

    float* wq_mp  = ws;
    float* wp_mp  = ws + 786432;
    float* q      = ws + 1048576;
    float* kn     = ws + 1572864;
    float* vn     = ws + 2097152;
    float* o_part = ws + 2621440;
    float* ml     = ws + 6815744;
    float* om     = ws + 6946816;

    hipLaunchKernelGGL(k_norm,    dim3(2048),  dim3(256), 0, stream, wqkv, wproj, wq_mp, wp_mp);
    hipLaunchKernelGGL(k_qkv,     dim3(96,4),  dim3(256), 0, stream, x, wq_mp, q, kn, vn);
    hipLaunchKernelGGL(k_attn,    dim3(32,8),  dim3(256), 0, stream, q, kc, vc, kn, vn, o_part, ml);
    hipLaunchKernelGGL(k_combine, dim3(32,4),  dim3(256), 0, stream, o_part, ml, om);
    hipLaunchKernelGGL(k_proj,    dim3(32,4),  dim3(256), 0, stream, om, wp_mp, x, out);
}

// Round 2
// 647.922 us; speedup vs baseline: 2.8894x; 2.8894x over previous
//
#include <hip/hip_runtime.h>
#include <math.h>

#define HW 256
#define CDIM 64
#define NHEAD 8
#define CFULL 512
#define BATCH 4
#define TFRAMES 64
#define NKEY (TFRAMES*HW)            // 16384
#define NSPLIT 8
#define KEYS_PER_SPLIT (NKEY/NSPLIT) // 2048
#define CHUNK 64
#define NCHUNK (KEYS_PER_SPLIT/CHUNK) // 32

#define KLOG10K_64 0.14391156634543589f  // ln(10000)/64

#define KP 68   // Ks LDS row pad (bytes stride 136, 8B-aligned, 2-way banks)
#define VP 72   // Vt LDS row pad (bytes stride 144, 8B-aligned)

typedef _Float16 half4  __attribute__((ext_vector_type(4)));
typedef _Float16 half2v __attribute__((ext_vector_type(2)));
typedef float    floatx4 __attribute__((ext_vector_type(4)));

#define MFMA16(a,b,c) __builtin_amdgcn_mfma_f32_16x16x16f16((a),(b),(c),0,0,0)

// ---------------- ws layout (floats) ----------------
// wq_mp   : [0]        786432
// wp_mp   : [786432]   262144
// q       : [1048576]  524288   (roped pos63)  [bm][p][ch]
// kn      : [1572864]  524288   (roped pos63)  [bm][p][ch]
// vn      : [2097152]  524288                  [bm][p][ch]
// o_part  : [2621440]  4194304                 [bm][s][ch][p]
// ml      : [6815744]  131072                  [bm][s][{m,l}][p]
// om      : [6946816]  524288                  [b][ch*8+head][p]

// ---- Kernel 1: mp-normalize weights ----
__global__ void k_norm(const float* __restrict__ wqkv, const float* __restrict__ wproj,
                       float* __restrict__ wq_mp, float* __restrict__ wp_mp) {
    int row = blockIdx.x;
    const float* src; float* dst;
    if (row < 1536) { src = wqkv + row*CFULL;        dst = wq_mp + row*CFULL; }
    else            { src = wproj + (row-1536)*CFULL; dst = wp_mp + (row-1536)*CFULL; }
    int t = threadIdx.x;
    float a = src[t], b = src[t+256];
    float v = a*a + b*b;
    #pragma unroll
    for (int o = 32; o >= 1; o >>= 1) v += __shfl_down(v, o, 64);
    __shared__ float red[4];
    if ((t & 63) == 0) red[t >> 6] = v;
    __syncthreads();
    float ss = red[0] + red[1] + red[2] + red[3];
    float norm = sqrtf(ss);
    const float s512 = 22.627416997969522f;
    float scale = 1.0f / ((1e-4f + norm / s512) * s512);
    dst[t]     = a * scale;
    dst[t+256] = b * scale;
}

// ---- Kernel 2: QKV projection + RoPE(pos=63) on q and new-k ----
__global__ void k_qkv(const float* __restrict__ x, const float* __restrict__ wq,
                      float* __restrict__ q, float* __restrict__ kn, float* __restrict__ vn) {
    int og = blockIdx.x;
    int b  = blockIdx.y;
    int p  = threadIdx.x;
    const float* xb = x + (long)b*CFULL*HW + p;
    float acc[16];
    #pragma unroll
    for (int i = 0; i < 16; i++) acc[i] = 0.f;
    int obase = og * 16;
    for (int c = 0; c < CFULL; c++) {
        float xv = xb[c*HW];
        #pragma unroll
        for (int i = 0; i < 16; i++) acc[i] += xv * wq[(obase+i)*CFULL + c];
    }
    int sec  = obase >> 9;
    int rem  = obase & 511;
    int head = rem >> 6;
    int chb  = rem & 63;
    float* dst = (sec == 0) ? q : (sec == 1) ? kn : vn;
    long base = ((long)((b*NHEAD + head)*HW + p)) * CDIM;
    if (sec == 2) {
        #pragma unroll
        for (int i = 0; i < 16; i++) dst[base + chb + i] = acc[i];
    } else {
        const float pos = 63.0f;
        #pragma unroll
        for (int i = 0; i < 16; i += 2) {
            int ch = chb + i;
            float fr = __expf(-(float)ch * KLOG10K_64);
            float sn, cs;
            __sincosf(pos * fr, &sn, &cs);
            float x1 = acc[i], x2 = acc[i+1];
            dst[base + ch]     = x1*cs - x2*sn;
            dst[base + ch + 1] = x1*sn + x2*cs;
        }
    }
}

// ---- Kernel 3: MFMA flash attention (f16 16x16x16) ----
// block = (bm, split), 512 threads = 8 waves; wave w owns queries [w*32, w*32+32)
// S^T = K·Q^T : A=K[key][ch] frags from LDS, B=Q^T per-wave register frags
// P^T C-layout == B-layout of next mfma  ->  O^T = V^T·P^T with no LDS round-trip
__global__ __launch_bounds__(512, 1) void k_attn(
        const float* __restrict__ q, const float* __restrict__ kc, const float* __restrict__ vc,
        const float* __restrict__ kn, const float* __restrict__ vn,
        float* __restrict__ o_part, float* __restrict__ ml) {
    const int bm = blockIdx.x;
    const int s  = blockIdx.y;
    const int t  = threadIdx.x;
    const int wave = t >> 6;
    const int lane = t & 63;
    const int ln   = lane & 15;
    const int quad = lane >> 4;
    const int qbase = wave * 32;

    __shared__ _Float16 Ks[CHUNK*KP];
    __shared__ _Float16 Vt[CDIM*VP];

    // Q fragments (scale 1/sqrt(64) folded in): qf[qt][ks]
    half4 qf[2][4];
    #pragma unroll
    for (int qt = 0; qt < 2; qt++)
        #pragma unroll
        for (int ks = 0; ks < 4; ks++) {
            const float* qp = q + ((long)(bm*HW + qbase + qt*16 + ln))*CDIM + ks*16 + quad*4;
            float4 f = *(const float4*)qp;
            half4 h;
            h[0] = (_Float16)(f.x*0.125f); h[1] = (_Float16)(f.y*0.125f);
            h[2] = (_Float16)(f.z*0.125f); h[3] = (_Float16)(f.w*0.125f);
            qf[qt][ks] = h;
        }

    floatx4 oacc[4][2];
    #pragma unroll
    for (int ct = 0; ct < 4; ct++)
        #pragma unroll
        for (int qt = 0; qt < 2; qt++)
            oacc[ct][qt] = (floatx4){0.f,0.f,0.f,0.f};
    float m_[2] = {-1e30f, -1e30f};
    float l_[2] = {0.f, 0.f};

    for (int chunk = 0; chunk < NCHUNK; chunk++) {
        int g0   = s*KEYS_PER_SPLIT + chunk*CHUNK;
        int tfr  = g0 >> 8;
        int poff = g0 & 255;
        const float *ksrc, *vsrc;
        bool rope;
        if (tfr < 63) {
            long base = ((long)((bm*63 + tfr)*HW + poff)) * CDIM;
            ksrc = kc + base; vsrc = vc + base; rope = true;
        } else {
            long base = ((long)(bm*HW + poff)) * CDIM;
            ksrc = kn + base; vsrc = vn + base; rope = false;  // already roped pos 63
        }
        float tpos = (float)tfr;
        __syncthreads();
        // --- K staging: 64 keys x 64 ch, rope + f16, [key][ch] pad KP ---
        #pragma unroll
        for (int it = 0; it < 2; it++) {
            int i   = t + it*512;
            int key = i >> 4;
            int ch  = (i & 15) * 4;
            float4 f = *(const float4*)(ksrc + key*CDIM + ch);
            if (rope) {
                float fr0 = __expf(-(float)ch       * KLOG10K_64);
                float fr1 = __expf(-(float)(ch + 2) * KLOG10K_64);
                float s0, c0, s1, c1;
                __sincosf(tpos*fr0, &s0, &c0);
                __sincosf(tpos*fr1, &s1, &c1);
                float4 r;
                r.x = f.x*c0 - f.y*s0;
                r.y = f.x*s0 + f.y*c0;
                r.z = f.z*c1 - f.w*s1;
                r.w = f.z*s1 + f.w*c1;
                f = r;
            }
            half4 h;
            h[0]=(_Float16)f.x; h[1]=(_Float16)f.y; h[2]=(_Float16)f.z; h[3]=(_Float16)f.w;
            *(half4*)&Ks[key*KP + ch] = h;
        }
        // --- V staging: transpose to Vt[ch][key] f16, pad VP ---
        {
            int kp = t & 31;        // key pair
            int ch = (t >> 5) * 4;  // 4 channels
            float4 a = *(const float4*)(vsrc + (2*kp  )*CDIM + ch);
            float4 b = *(const float4*)(vsrc + (2*kp+1)*CDIM + ch);
            float av[4] = {a.x,a.y,a.z,a.w};
            float bv[4] = {b.x,b.y,b.z,b.w};
            #pragma unroll
            for (int i = 0; i < 4; i++) {
                half2v h; h[0] = (_Float16)av[i]; h[1] = (_Float16)bv[i];
                *(half2v*)&Vt[(ch+i)*VP + 2*kp] = h;
            }
        }
        __syncthreads();

        // --- S^T = K·Q^T : sacc[kt][qt], value S^T[key=kt*16+quad*4+r][q=qt*16+ln]
        floatx4 sacc[4][2];
        #pragma unroll
        for (int kt = 0; kt < 4; kt++)
            #pragma unroll
            for (int qt = 0; qt < 2; qt++)
                sacc[kt][qt] = (floatx4){0.f,0.f,0.f,0.f};
        #pragma unroll
        for (int ks = 0; ks < 4; ks++) {
            half4 kf[4];
            #pragma unroll
            for (int kt = 0; kt < 4; kt++)
                kf[kt] = *(const half4*)&Ks[(kt*16 + ln)*KP + ks*16 + quad*4];
            #pragma unroll
            for (int kt = 0; kt < 4; kt++)
                #pragma unroll
                for (int qt = 0; qt < 2; qt++)
                    sacc[kt][qt] = MFMA16(kf[kt], qf[qt][ks], sacc[kt][qt]);
        }

        // --- online softmax per query column; P^T straight into B-frags ---
        half4 ptf[4][2];
        #pragma unroll
        for (int qt = 0; qt < 2; qt++) {
            float tmax = -1e30f;
            #pragma unroll
            for (int kt = 0; kt < 4; kt++)
                #pragma unroll
                for (int r = 0; r < 4; r++)
                    tmax = fmaxf(tmax, sacc[kt][qt][r]);
            tmax = fmaxf(tmax, __shfl_xor(tmax, 16, 64));
            tmax = fmaxf(tmax, __shfl_xor(tmax, 32, 64));
            float mnew  = fmaxf(m_[qt], tmax);
            float alpha = __expf(m_[qt] - mnew);
            float lsum = 0.f;
            #pragma unroll
            for (int kt = 0; kt < 4; kt++) {
                half4 ph;
                #pragma unroll
                for (int r = 0; r < 4; r++) {
                    float p = __expf(sacc[kt][qt][r] - mnew);
                    lsum += p;
                    ph[r] = (_Float16)p;
                }
                ptf[kt][qt] = ph;
            }
            lsum += __shfl_xor(lsum, 16, 64);
            lsum += __shfl_xor(lsum, 32, 64);
            l_[qt] = l_[qt]*alpha + lsum;
            m_[qt] = mnew;
            #pragma unroll
            for (int ct = 0; ct < 4; ct++)
                #pragma unroll
                for (int r = 0; r < 4; r++)
                    oacc[ct][qt][r] *= alpha;
        }

        // --- O^T += V^T · P^T ---
        #pragma unroll
        for (int kt = 0; kt < 4; kt++) {
            half4 vf[4];
            #pragma unroll
            for (int ct = 0; ct < 4; ct++)
                vf[ct] = *(const half4*)&Vt[(ct*16 + ln)*VP + kt*16 + quad*4];
            #pragma unroll
            for (int ct = 0; ct < 4; ct++)
                #pragma unroll
                for (int qt = 0; qt < 2; qt++)
                    oacc[ct][qt] = MFMA16(vf[ct], ptf[kt][qt], oacc[ct][qt]);
        }
    }

    // --- epilogue: unnormalized O^T + (m,l) per query ---
    long ob = ((long)(bm*NSPLIT + s)) * CDIM * HW;
    #pragma unroll
    for (int ct = 0; ct < 4; ct++)
        #pragma unroll
        for (int qt = 0; qt < 2; qt++)
            #pragma unroll
            for (int r = 0; r < 4; r++)
                o_part[ob + (long)(ct*16 + quad*4 + r)*HW + qbase + qt*16 + ln] = oacc[ct][qt][r];
    long mb = ((long)(bm*NSPLIT + s)) * 2 * HW;
    if (quad == 0) {
        #pragma unroll
        for (int qt = 0; qt < 2; qt++) {
            int qq = qbase + qt*16 + ln;
            ml[mb + qq]      = m_[qt];
            ml[mb + HW + qq] = l_[qt];
        }
    }
}

// ---- Kernel 4: combine split partials ----
__global__ void k_combine(const float* __restrict__ o_part, const float* __restrict__ ml,
                          float* __restrict__ om) {
    int bm  = blockIdx.x;
    int chg = blockIdx.y;
    int p   = threadIdx.x;
    float ms[NSPLIT], ls[NSPLIT];
    float mmax = -1e30f;
    #pragma unroll
    for (int s2 = 0; s2 < NSPLIT; s2++) {
        long mb = ((long)(bm*NSPLIT + s2)) * 2 * HW;
        ms[s2] = ml[mb + p];
        ls[s2] = ml[mb + HW + p];
        mmax = fmaxf(mmax, ms[s2]);
    }
    float wgt[NSPLIT];
    float wsum = 0.f;
    #pragma unroll
    for (int s2 = 0; s2 < NSPLIT; s2++) { wgt[s2] = __expf(ms[s2]-mmax); wsum += wgt[s2]*ls[s2]; }
    float inv = 1.0f / wsum;
    int b = bm >> 3, head = bm & 7;
    for (int ch = chg*16; ch < chg*16 + 16; ch++) {
        float acc = 0.f;
        #pragma unroll
        for (int s2 = 0; s2 < NSPLIT; s2++)
            acc += wgt[s2] * o_part[(((long)(bm*NSPLIT + s2))*CDIM + ch)*HW + p];
        om[((long)(b*CFULL + ch*NHEAD + head))*HW + p] = acc * inv;
    }
}

// ---- Kernel 5: output projection + mp_sum residual ----
__global__ void k_proj(const float* __restrict__ om, const float* __restrict__ wp,
                       const float* __restrict__ x, float* __restrict__ out) {
    int og = blockIdx.x;
    int b  = blockIdx.y;
    int p  = threadIdx.x;
    float acc[16];
    #pragma unroll
    for (int i = 0; i < 16; i++) acc[i] = 0.f;
    const float* ob = om + (long)b*CFULL*HW + p;
    for (int c = 0; c < CFULL; c++) {
        float ov = ob[c*HW];
        #pragma unroll
        for (int i = 0; i < 16; i++) acc[i] += ov * wp[(og*16+i)*CFULL + c];
    }
    const float inv_mp = 1.3130643285972254f;
    #pragma unroll
    for (int i = 0; i < 16; i++) {
        int oc = og*16 + i;
        long idx = ((long)(b*CFULL + oc))*HW + p;
        out[idx] = (x[idx]*0.7f + acc[i]*0.3f) * inv_mp;
    }
}

extern "C" void kernel_launch(void* const* d_in, const int* in_sizes, int n_in,
                              void* d_out, int out_size, void* d_ws, size_t ws_size,
                              hipStream_t stream) {
    const float* x     = (const float*)d_in[0];
    const float* kc    = (const float*)d_in[1];
    const float* vc    = (const float*)d_in[2];
    const float* wqkv  = (const float*)d_in[3];
    const float* wproj = (const float*)d_in[4];
    float* out = (float*)d_out;
    float* ws  = (float*)d_ws;

    float* wq_mp  = ws;
    float* wp_mp  = ws + 786432;
    float* q      = ws + 1048576;
    float* kn     = ws + 1572864;
    float* vn     = ws + 2097152;
    float* o_part = ws + 2621440;
    float* ml     = ws + 6815744;
    float* om     = ws + 6946816;

    hipLaunchKernelGGL(k_norm,    dim3(2048),  dim3(256), 0, stream, wqkv, wproj, wq_mp, wp_mp);
    hipLaunchKernelGGL(k_qkv,     dim3(96,4),  dim3(256), 0, stream, x, wq_mp, q, kn, vn);
    hipLaunchKernelGGL(k_attn,    dim3(32,8),  dim3(512), 0, stream, q, kc, vc, kn, vn, o_part, ml);
    hipLaunchKernelGGL(k_combine, dim3(32,4),  dim3(256), 0, stream, o_part, ml, om);
    hipLaunchKernelGGL(k_proj,    dim3(32,4),  dim3(256), 0, stream, om, wp_mp, x, out);
}

// Round 3
// 348.085 us; speedup vs baseline: 5.3783x; 1.8614x over previous
//
#include <hip/hip_runtime.h>
#include <math.h>

#define HW 256
#define CDIM 64
#define NHEAD 8
#define CFULL 512
#define BATCH 4
#define TFRAMES 64
#define NKEY (TFRAMES*HW)            // 16384
#define NSPLIT 8
#define KEYS_PER_SPLIT (NKEY/NSPLIT) // 2048
#define CHUNK 64
#define NCHUNK (KEYS_PER_SPLIT/CHUNK) // 32

#define KLOG10K_64 0.14391156634543589f  // ln(10000)/64

#define KP 68   // attn Ks LDS pad (halves)
#define VP 72   // attn Vt LDS pad (halves)
#define PA 72   // gemm LDS pitch (halves): 64 + 8

typedef _Float16 half4  __attribute__((ext_vector_type(4)));
typedef _Float16 half2v __attribute__((ext_vector_type(2)));
typedef float    floatx4 __attribute__((ext_vector_type(4)));

#define MFMA16(a,b,c) __builtin_amdgcn_mfma_f32_16x16x16f16((a),(b),(c),0,0,0)

// ---------------- ws layout (float offsets) ----------------
// wq_h   : [0]        1536*512 f16                (mp-normalized, A-op)
// wp_h   : [393216]   512*512 f16, cols permuted k'=head*64+ch
// xt_h   : [524288]   4*256*512 f16               x transposed [b][p][c]
// q      : [786432]   524288 f32  (roped pos63)   [bm][p][ch]
// kn     : [1310720]  524288 f32  (roped pos63)   [bm][p][ch]
// vn     : [1835008]  524288 f32                  [bm][p][ch]
// o_part : [2359296]  4194304 f32                 [bm][s][ch][p]
// ml     : [6553600]  131072 f32                  [bm][s][{m,l}][p]
// omt_h  : [6684672]  4*256*512 f16               [b][p][k'=head*64+ch]
// end 6946816 floats = 27.8 MB

// ---- Kernel 1: mp-normalize weights -> f16 (wp columns permuted) ----
__global__ void k_norm(const float* __restrict__ wqkv, const float* __restrict__ wproj,
                       _Float16* __restrict__ wq_h, _Float16* __restrict__ wp_h) {
    int row = blockIdx.x;
    int t = threadIdx.x;
    float a, b;
    const float* src;
    if (row < 1536) {
        src = wqkv + row*CFULL;
        a = src[t]; b = src[t+256];
    } else {
        src = wproj + (row-1536)*CFULL;
        int ic1 = (t & 63)*8 + (t >> 6);
        int k2 = t + 256;
        int ic2 = (k2 & 63)*8 + (k2 >> 6);
        a = src[ic1]; b = src[ic2];
    }
    float v = a*a + b*b;
    #pragma unroll
    for (int o = 32; o >= 1; o >>= 1) v += __shfl_down(v, o, 64);
    __shared__ float red[4];
    if ((t & 63) == 0) red[t >> 6] = v;
    __syncthreads();
    float ss = red[0] + red[1] + red[2] + red[3];
    float norm = sqrtf(ss);
    const float s512 = 22.627416997969522f;
    float scale = 1.0f / ((1e-4f + norm / s512) * s512);
    if (row < 1536) {
        wq_h[row*CFULL + t]       = (_Float16)(a*scale);
        wq_h[row*CFULL + t + 256] = (_Float16)(b*scale);
    } else {
        int r2 = row - 1536;
        wp_h[r2*CFULL + t]       = (_Float16)(a*scale);
        wp_h[r2*CFULL + t + 256] = (_Float16)(b*scale);
    }
}

// ---- Kernel 1b: transpose x -> xt_h[b][p][c] f16 ----
__global__ void k_xT(const float* __restrict__ x, _Float16* __restrict__ xt_h) {
    int pb = blockIdx.x;   // 4 blocks of 64 p
    int cb = blockIdx.y;   // 8 blocks of 64 c
    int b  = blockIdx.z;
    int t  = threadIdx.x;
    int p  = pb*64 + (t & 63);
    int c0 = cb*64 + (t >> 6)*16;
    half4 h[4];
    #pragma unroll
    for (int j = 0; j < 16; j++) {
        float val = x[((long)(b*CFULL + c0 + j))*HW + p];
        h[j >> 2][j & 3] = (_Float16)val;
    }
    _Float16* dst = xt_h + ((long)(b*HW + p))*CFULL + c0;
    #pragma unroll
    for (int j = 0; j < 4; j++) *(half4*)(dst + j*4) = h[j];
}

// ---- Kernel 2: QKV projection GEMM (MFMA) + RoPE(pos63) epilogue ----
// C[o][p] = sum_c wq_h[o][c] * xt_h[p][c];  64x64 tile, KC=64, 4 waves
__global__ __launch_bounds__(256) void k_gemm_qkv(
        const _Float16* __restrict__ wq_h, const _Float16* __restrict__ xt_h,
        float* __restrict__ q, float* __restrict__ kn, float* __restrict__ vn) {
    int bx = blockIdx.x;   // 24 M-tiles
    int by = blockIdx.y;   // 4 N-tiles
    int b  = blockIdx.z;
    int t  = threadIdx.x;
    int wave = t >> 6, lane = t & 63, ln = lane & 15, quad = lane >> 4;
    __shared__ _Float16 As[64*PA];
    __shared__ _Float16 Bs[64*PA];
    int obase = bx*64, pbase = by*64;
    int lrow = t >> 2, lseg = t & 3;
    const _Float16* ag = wq_h + (long)(obase + lrow)*CFULL + lseg*16;
    const _Float16* bg = xt_h + (long)(b*HW + pbase + lrow)*CFULL + lseg*16;
    uint4 ar0 = *(const uint4*)ag,     ar1 = *(const uint4*)(ag + 8);
    uint4 br0 = *(const uint4*)bg,     br1 = *(const uint4*)(bg + 8);
    floatx4 acc[4];
    #pragma unroll
    for (int nt = 0; nt < 4; nt++) acc[nt] = (floatx4){0.f,0.f,0.f,0.f};
    for (int kc = 0; kc < 8; kc++) {
        __syncthreads();
        *(uint4*)&As[lrow*PA + lseg*16]     = ar0;
        *(uint4*)&As[lrow*PA + lseg*16 + 8] = ar1;
        *(uint4*)&Bs[lrow*PA + lseg*16]     = br0;
        *(uint4*)&Bs[lrow*PA + lseg*16 + 8] = br1;
        __syncthreads();
        if (kc < 7) {
            const _Float16* an = ag + (kc+1)*64;
            const _Float16* bn = bg + (kc+1)*64;
            ar0 = *(const uint4*)an; ar1 = *(const uint4*)(an + 8);
            br0 = *(const uint4*)bn; br1 = *(const uint4*)(bn + 8);
        }
        #pragma unroll
        for (int ks = 0; ks < 4; ks++) {
            half4 af = *(const half4*)&As[(wave*16 + ln)*PA + ks*16 + quad*4];
            #pragma unroll
            for (int nt = 0; nt < 4; nt++) {
                half4 bf = *(const half4*)&Bs[(nt*16 + ln)*PA + ks*16 + quad*4];
                acc[nt] = MFMA16(af, bf, acc[nt]);
            }
        }
    }
    // epilogue: D row o = obase + wave*16 + quad*4 + r ; col p = pbase + nt*16 + ln
    int sec  = obase >> 9;
    int head = (obase >> 6) & 7;
    int bm   = b*NHEAD + head;
    int ch0  = wave*16 + quad*4;
    if (sec == 2) {
        #pragma unroll
        for (int nt = 0; nt < 4; nt++) {
            int p = pbase + nt*16 + ln;
            float4 o4; o4.x = acc[nt][0]; o4.y = acc[nt][1]; o4.z = acc[nt][2]; o4.w = acc[nt][3];
            *(float4*)&vn[((long)(bm*HW + p))*CDIM + ch0] = o4;
        }
    } else {
        float* dst = (sec == 0) ? q : kn;
        float fr0 = __expf(-(float)ch0       * KLOG10K_64);
        float fr1 = __expf(-(float)(ch0 + 2) * KLOG10K_64);
        float s0, c0, s1, c1;
        __sincosf(63.0f*fr0, &s0, &c0);
        __sincosf(63.0f*fr1, &s1, &c1);
        #pragma unroll
        for (int nt = 0; nt < 4; nt++) {
            int p = pbase + nt*16 + ln;
            float4 o4;
            o4.x = acc[nt][0]*c0 - acc[nt][1]*s0;
            o4.y = acc[nt][0]*s0 + acc[nt][1]*c0;
            o4.z = acc[nt][2]*c1 - acc[nt][3]*s1;
            o4.w = acc[nt][2]*s1 + acc[nt][3]*c1;
            *(float4*)&dst[((long)(bm*HW + p))*CDIM + ch0] = o4;
        }
    }
}

// ---- Kernel 3: MFMA flash attention (unchanged from round 2) ----
__global__ __launch_bounds__(512, 1) void k_attn(
        const float* __restrict__ q, const float* __restrict__ kc, const float* __restrict__ vc,
        const float* __restrict__ kn, const float* __restrict__ vn,
        float* __restrict__ o_part, float* __restrict__ ml) {
    const int bm = blockIdx.x;
    const int s  = blockIdx.y;
    const int t  = threadIdx.x;
    const int wave = t >> 6;
    const int lane = t & 63;
    const int ln   = lane & 15;
    const int quad = lane >> 4;
    const int qbase = wave * 32;

    __shared__ _Float16 Ks[CHUNK*KP];
    __shared__ _Float16 Vt[CDIM*VP];

    half4 qf[2][4];
    #pragma unroll
    for (int qt = 0; qt < 2; qt++)
        #pragma unroll
        for (int ks = 0; ks < 4; ks++) {
            const float* qp = q + ((long)(bm*HW + qbase + qt*16 + ln))*CDIM + ks*16 + quad*4;
            float4 f = *(const float4*)qp;
            half4 h;
            h[0] = (_Float16)(f.x*0.125f); h[1] = (_Float16)(f.y*0.125f);
            h[2] = (_Float16)(f.z*0.125f); h[3] = (_Float16)(f.w*0.125f);
            qf[qt][ks] = h;
        }

    floatx4 oacc[4][2];
    #pragma unroll
    for (int ct = 0; ct < 4; ct++)
        #pragma unroll
        for (int qt = 0; qt < 2; qt++)
            oacc[ct][qt] = (floatx4){0.f,0.f,0.f,0.f};
    float m_[2] = {-1e30f, -1e30f};
    float l_[2] = {0.f, 0.f};

    for (int chunk = 0; chunk < NCHUNK; chunk++) {
        int g0   = s*KEYS_PER_SPLIT + chunk*CHUNK;
        int tfr  = g0 >> 8;
        int poff = g0 & 255;
        const float *ksrc, *vsrc;
        bool rope;
        if (tfr < 63) {
            long base = ((long)((bm*63 + tfr)*HW + poff)) * CDIM;
            ksrc = kc + base; vsrc = vc + base; rope = true;
        } else {
            long base = ((long)(bm*HW + poff)) * CDIM;
            ksrc = kn + base; vsrc = vn + base; rope = false;
        }
        float tpos = (float)tfr;
        __syncthreads();
        #pragma unroll
        for (int it = 0; it < 2; it++) {
            int i   = t + it*512;
            int key = i >> 4;
            int ch  = (i & 15) * 4;
            float4 f = *(const float4*)(ksrc + key*CDIM + ch);
            if (rope) {
                float fr0 = __expf(-(float)ch       * KLOG10K_64);
                float fr1 = __expf(-(float)(ch + 2) * KLOG10K_64);
                float s0, c0, s1, c1;
                __sincosf(tpos*fr0, &s0, &c0);
                __sincosf(tpos*fr1, &s1, &c1);
                float4 r;
                r.x = f.x*c0 - f.y*s0;
                r.y = f.x*s0 + f.y*c0;
                r.z = f.z*c1 - f.w*s1;
                r.w = f.z*s1 + f.w*c1;
                f = r;
            }
            half4 h;
            h[0]=(_Float16)f.x; h[1]=(_Float16)f.y; h[2]=(_Float16)f.z; h[3]=(_Float16)f.w;
            *(half4*)&Ks[key*KP + ch] = h;
        }
        {
            int kp = t & 31;
            int ch = (t >> 5) * 4;
            float4 a = *(const float4*)(vsrc + (2*kp  )*CDIM + ch);
            float4 b = *(const float4*)(vsrc + (2*kp+1)*CDIM + ch);
            float av[4] = {a.x,a.y,a.z,a.w};
            float bv[4] = {b.x,b.y,b.z,b.w};
            #pragma unroll
            for (int i = 0; i < 4; i++) {
                half2v h; h[0] = (_Float16)av[i]; h[1] = (_Float16)bv[i];
                *(half2v*)&Vt[(ch+i)*VP + 2*kp] = h;
            }
        }
        __syncthreads();

        floatx4 sacc[4][2];
        #pragma unroll
        for (int kt = 0; kt < 4; kt++)
            #pragma unroll
            for (int qt = 0; qt < 2; qt++)
                sacc[kt][qt] = (floatx4){0.f,0.f,0.f,0.f};
        #pragma unroll
        for (int ks = 0; ks < 4; ks++) {
            half4 kf[4];
            #pragma unroll
            for (int kt = 0; kt < 4; kt++)
                kf[kt] = *(const half4*)&Ks[(kt*16 + ln)*KP + ks*16 + quad*4];
            #pragma unroll
            for (int kt = 0; kt < 4; kt++)
                #pragma unroll
                for (int qt = 0; qt < 2; qt++)
                    sacc[kt][qt] = MFMA16(kf[kt], qf[qt][ks], sacc[kt][qt]);
        }

        half4 ptf[4][2];
        #pragma unroll
        for (int qt = 0; qt < 2; qt++) {
            float tmax = -1e30f;
            #pragma unroll
            for (int kt = 0; kt < 4; kt++)
                #pragma unroll
                for (int r = 0; r < 4; r++)
                    tmax = fmaxf(tmax, sacc[kt][qt][r]);
            tmax = fmaxf(tmax, __shfl_xor(tmax, 16, 64));
            tmax = fmaxf(tmax, __shfl_xor(tmax, 32, 64));
            float mnew  = fmaxf(m_[qt], tmax);
            float alpha = __expf(m_[qt] - mnew);
            float lsum = 0.f;
            #pragma unroll
            for (int kt = 0; kt < 4; kt++) {
                half4 ph;
                #pragma unroll
                for (int r = 0; r < 4; r++) {
                    float p = __expf(sacc[kt][qt][r] - mnew);
                    lsum += p;
                    ph[r] = (_Float16)p;
                }
                ptf[kt][qt] = ph;
            }
            lsum += __shfl_xor(lsum, 16, 64);
            lsum += __shfl_xor(lsum, 32, 64);
            l_[qt] = l_[qt]*alpha + lsum;
            m_[qt] = mnew;
            #pragma unroll
            for (int ct = 0; ct < 4; ct++)
                #pragma unroll
                for (int r = 0; r < 4; r++)
                    oacc[ct][qt][r] *= alpha;
        }

        #pragma unroll
        for (int kt = 0; kt < 4; kt++) {
            half4 vf[4];
            #pragma unroll
            for (int ct = 0; ct < 4; ct++)
                vf[ct] = *(const half4*)&Vt[(ct*16 + ln)*VP + kt*16 + quad*4];
            #pragma unroll
            for (int ct = 0; ct < 4; ct++)
                #pragma unroll
                for (int qt = 0; qt < 2; qt++)
                    oacc[ct][qt] = MFMA16(vf[ct], ptf[kt][qt], oacc[ct][qt]);
        }
    }

    long ob = ((long)(bm*NSPLIT + s)) * CDIM * HW;
    #pragma unroll
    for (int ct = 0; ct < 4; ct++)
        #pragma unroll
        for (int qt = 0; qt < 2; qt++)
            #pragma unroll
            for (int r = 0; r < 4; r++)
                o_part[ob + (long)(ct*16 + quad*4 + r)*HW + qbase + qt*16 + ln] = oacc[ct][qt][r];
    long mb = ((long)(bm*NSPLIT + s)) * 2 * HW;
    if (quad == 0) {
        #pragma unroll
        for (int qt = 0; qt < 2; qt++) {
            int qq = qbase + qt*16 + ln;
            ml[mb + qq]      = m_[qt];
            ml[mb + HW + qq] = l_[qt];
        }
    }
}

// ---- Kernel 4: combine split partials -> omt_h[b][p][head*64+ch] f16 ----
__global__ void k_combine(const float* __restrict__ o_part, const float* __restrict__ ml,
                          _Float16* __restrict__ omt_h) {
    int bm  = blockIdx.x;
    int chg = blockIdx.y;
    int p   = threadIdx.x;
    float ms[NSPLIT], ls[NSPLIT];
    float mmax = -1e30f;
    #pragma unroll
    for (int s2 = 0; s2 < NSPLIT; s2++) {
        long mb = ((long)(bm*NSPLIT + s2)) * 2 * HW;
        ms[s2] = ml[mb + p];
        ls[s2] = ml[mb + HW + p];
        mmax = fmaxf(mmax, ms[s2]);
    }
    float wgt[NSPLIT];
    float wsum = 0.f;
    #pragma unroll
    for (int s2 = 0; s2 < NSPLIT; s2++) { wgt[s2] = __expf(ms[s2]-mmax); wsum += wgt[s2]*ls[s2]; }
    float inv = 1.0f / wsum;
    float acc[16];
    #pragma unroll
    for (int i = 0; i < 16; i++) acc[i] = 0.f;
    #pragma unroll
    for (int s2 = 0; s2 < NSPLIT; s2++) {
        float w = wgt[s2];
        const float* src = o_part + (((long)(bm*NSPLIT + s2))*CDIM + chg*16)*HW + p;
        #pragma unroll
        for (int i = 0; i < 16; i++) acc[i] += w * src[(long)i*HW];
    }
    int b = bm >> 3, head = bm & 7;
    _Float16* dst = omt_h + ((long)(b*HW + p))*CFULL + head*64 + chg*16;
    half4 h[4];
    #pragma unroll
    for (int i = 0; i < 16; i++) h[i >> 2][i & 3] = (_Float16)(acc[i]*inv);
    #pragma unroll
    for (int j = 0; j < 4; j++) *(half4*)(dst + j*4) = h[j];
}

// ---- Kernel 5: output projection GEMM (MFMA) + mp_sum residual ----
__global__ __launch_bounds__(256) void k_gemm_proj(
        const _Float16* __restrict__ wp_h, const _Float16* __restrict__ omt_h,
        const float* __restrict__ x, float* __restrict__ out) {
    int bx = blockIdx.x;   // 8 M-tiles
    int by = blockIdx.y;   // 4 N-tiles
    int b  = blockIdx.z;
    int t  = threadIdx.x;
    int wave = t >> 6, lane = t & 63, ln = lane & 15, quad = lane >> 4;
    __shared__ _Float16 As[64*PA];
    __shared__ _Float16 Bs[64*PA];
    int obase = bx*64, pbase = by*64;
    int lrow = t >> 2, lseg = t & 3;
    const _Float16* ag = wp_h  + (long)(obase + lrow)*CFULL + lseg*16;
    const _Float16* bg = omt_h + (long)(b*HW + pbase + lrow)*CFULL + lseg*16;
    uint4 ar0 = *(const uint4*)ag, ar1 = *(const uint4*)(ag + 8);
    uint4 br0 = *(const uint4*)bg, br1 = *(const uint4*)(bg + 8);
    floatx4 acc[4];
    #pragma unroll
    for (int nt = 0; nt < 4; nt++) acc[nt] = (floatx4){0.f,0.f,0.f,0.f};
    for (int kc = 0; kc < 8; kc++) {
        __syncthreads();
        *(uint4*)&As[lrow*PA + lseg*16]     = ar0;
        *(uint4*)&As[lrow*PA + lseg*16 + 8] = ar1;
        *(uint4*)&Bs[lrow*PA + lseg*16]     = br0;
        *(uint4*)&Bs[lrow*PA + lseg*16 + 8] = br1;
        __syncthreads();
        if (kc < 7) {
            const _Float16* an = ag + (kc+1)*64;
            const _Float16* bn = bg + (kc+1)*64;
            ar0 = *(const uint4*)an; ar1 = *(const uint4*)(an + 8);
            br0 = *(const uint4*)bn; br1 = *(const uint4*)(bn + 8);
        }
        #pragma unroll
        for (int ks = 0; ks < 4; ks++) {
            half4 af = *(const half4*)&As[(wave*16 + ln)*PA + ks*16 + quad*4];
            #pragma unroll
            for (int nt = 0; nt < 4; nt++) {
                half4 bf = *(const half4*)&Bs[(nt*16 + ln)*PA + ks*16 + quad*4];
                acc[nt] = MFMA16(af, bf, acc[nt]);
            }
        }
    }
    const float inv_mp = 1.3130643285972254f;
    int o0 = obase + wave*16 + quad*4;
    #pragma unroll
    for (int nt = 0; nt < 4; nt++) {
        int p = pbase + nt*16 + ln;
        #pragma unroll
        for (int r = 0; r < 4; r++) {
            long idx = ((long)(b*CFULL + o0 + r))*HW + p;
            out[idx] = (x[idx]*0.7f + acc[nt][r]*0.3f) * inv_mp;
        }
    }
}

extern "C" void kernel_launch(void* const* d_in, const int* in_sizes, int n_in,
                              void* d_out, int out_size, void* d_ws, size_t ws_size,
                              hipStream_t stream) {
    const float* x     = (const float*)d_in[0];
    const float* kc    = (const float*)d_in[1];
    const float* vc    = (const float*)d_in[2];
    const float* wqkv  = (const float*)d_in[3];
    const float* wproj = (const float*)d_in[4];
    float* out = (float*)d_out;
    float* ws  = (float*)d_ws;

    _Float16* wq_h  = (_Float16*)ws;
    _Float16* wp_h  = (_Float16*)(ws + 393216);
    _Float16* xt_h  = (_Float16*)(ws + 524288);
    float* q        = ws + 786432;
    float* kn       = ws + 1310720;
    float* vn       = ws + 1835008;
    float* o_part   = ws + 2359296;
    float* ml       = ws + 6553600;
    _Float16* omt_h = (_Float16*)(ws + 6684672);

    hipLaunchKernelGGL(k_norm,      dim3(2048),    dim3(256), 0, stream, wqkv, wproj, wq_h, wp_h);
    hipLaunchKernelGGL(k_xT,        dim3(4,8,4),   dim3(256), 0, stream, x, xt_h);
    hipLaunchKernelGGL(k_gemm_qkv,  dim3(24,4,4),  dim3(256), 0, stream, wq_h, xt_h, q, kn, vn);
    hipLaunchKernelGGL(k_attn,      dim3(32,8),    dim3(512), 0, stream, q, kc, vc, kn, vn, o_part, ml);
    hipLaunchKernelGGL(k_combine,   dim3(32,4),    dim3(256), 0, stream, o_part, ml, omt_h);
    hipLaunchKernelGGL(k_gemm_proj, dim3(8,4,4),   dim3(256), 0, stream, wp_h, omt_h, x, out);
}